// Round 3
// baseline (234345.801 us; speedup 1.0000x reference)
//
#include <hip/hip_runtime.h>
#include <math.h>

// 2-layer GRU, T=4096, B=64, H=512, input=1. Output = final hidden (2,64,512) f32.
//
// R3: PERSISTENT kernel. 192 WGs (<=256 CUs -> all co-resident), weights
// staged in LDS once, 4096 steps inside one kernel with a device-scope
// atomic grid barrier per step. States stored TRANSPOSED hT[k][b], lane=b:
// all global h accesses coalesce; weight reads are uniform ds_read_b128
// broadcasts; no cross-lane ops.
//   L0: WGs [0,64):  8 j per WG (wave w owns j0=jg*8+2w, j1=j0+1), K=512
//   L1: WGs [64,192): 4 j per WG (wave w owns j=jg*4+w), K=1024 (y0 | h1)
// Software skew as R2: iter t computes L0 state t and L1 state t-1.
// ws: hT0[2][512][64] | hT1[2][512][64] | cnt  (512KB + 4B)

#define TT 4096
#define BB 64
#define HH 512
#define NWG 192
#define L0WG 64

__device__ __forceinline__ float sigm(float v) { return 1.0f / (1.0f + expf(-v)); }

__global__ __launch_bounds__(256) void zero_k(float* p, int n) {
    int i = blockIdx.x * 256 + threadIdx.x;
    if (i < n) p[i] = 0.0f;
}

__device__ __forceinline__ void grid_barrier(unsigned* cnt, int t, int tid) {
    __syncthreads();
    if (tid == 0) {
        __hip_atomic_fetch_add(cnt, 1u, __ATOMIC_RELEASE, __HIP_MEMORY_SCOPE_AGENT);
        const unsigned target = (unsigned)(t + 1) * NWG;
        while (__hip_atomic_load(cnt, __ATOMIC_ACQUIRE, __HIP_MEMORY_SCOPE_AGENT) < target)
            __builtin_amdgcn_s_sleep(4);
    }
    __syncthreads();
}

__global__ __launch_bounds__(256) void gru_persist(
    const float* __restrict__ x,
    const float* __restrict__ wih0, const float* __restrict__ whh0,
    const float* __restrict__ bih0, const float* __restrict__ bhh0,
    const float* __restrict__ wih1, const float* __restrict__ whh1,
    const float* __restrict__ bih1, const float* __restrict__ bhh1,
    float* __restrict__ ws)
{
    __shared__ float4 lds4[4096];          // 64 KB
    float* lds = (float*)lds4;
    float* hT0 = ws;                        // [2][512][64]
    float* hT1 = ws + 2 * HH * BB;          // [2][512][64]
    unsigned* cnt = (unsigned*)(ws + 4 * HH * BB);

    const int tid  = threadIdx.x;
    const int lane = tid & 63;              // batch index
    const int w    = tid >> 6;              // wave 0..3
    const int id   = blockIdx.x;

    if (id < L0WG) {
        // ================= Layer 0 =================
        const int jg = id;
        for (int idx = tid; idx < 24 * 512; idx += 256) {
            int k = idx & 511, row = idx >> 9;
            int jl = row / 3, g = row - 3 * jl;
            lds[k * 32 + jl * 4 + g] = whh0[(size_t)(g * HH + jg * 8 + jl) * HH + k];
        }
        const int j0 = jg * 8 + w * 2, j1 = j0 + 1;
        const float wir0 = wih0[j0], wiz0 = wih0[HH + j0], win0 = wih0[2 * HH + j0];
        const float wir1 = wih0[j1], wiz1 = wih0[HH + j1], win1 = wih0[2 * HH + j1];
        const float br0  = bih0[j0] + bhh0[j0];
        const float bz0  = bih0[HH + j0] + bhh0[HH + j0];
        const float bnx0 = bih0[2 * HH + j0], bnh0 = bhh0[2 * HH + j0];
        const float br1  = bih0[j1] + bhh0[j1];
        const float bz1  = bih0[HH + j1] + bhh0[HH + j1];
        const float bnx1 = bih0[2 * HH + j1], bnh1 = bhh0[2 * HH + j1];
        __syncthreads();

        for (int t = 0; t <= TT; ++t) {
            if (t < TT) {
                const float* hin  = hT0 + (size_t)((t + 1) & 1) * HH * BB;
                float*       hout = hT0 + (size_t)(t & 1) * HH * BB;
                const float xv    = x[(size_t)t * BB + lane];
                const float hold0 = hin[j0 * 64 + lane];
                const float hold1 = hin[j1 * 64 + lane];
                float a0r = 0.f, a0z = 0.f, a0n = 0.f;
                float a1r = 0.f, a1z = 0.f, a1n = 0.f;
                #pragma unroll 8
                for (int k = 0; k < HH; ++k) {
                    const float hv = hin[k * 64 + lane];
                    const float4 wA = lds4[k * 8 + w * 2];
                    const float4 wB = lds4[k * 8 + w * 2 + 1];
                    a0r += wA.x * hv; a0z += wA.y * hv; a0n += wA.z * hv;
                    a1r += wB.x * hv; a1z += wB.y * hv; a1n += wB.z * hv;
                }
                {
                    const float r = sigm(xv * wir0 + br0 + a0r);
                    const float z = sigm(xv * wiz0 + bz0 + a0z);
                    const float n = tanhf(xv * win0 + bnx0 + r * (a0n + bnh0));
                    hout[j0 * 64 + lane] = (1.0f - z) * n + z * hold0;
                }
                {
                    const float r = sigm(xv * wir1 + br1 + a1r);
                    const float z = sigm(xv * wiz1 + bz1 + a1z);
                    const float n = tanhf(xv * win1 + bnx1 + r * (a1n + bnh1));
                    hout[j1 * 64 + lane] = (1.0f - z) * n + z * hold1;
                }
            }
            grid_barrier(cnt, t, tid);
        }
    } else {
        // ================= Layer 1 =================
        const int jg = id - L0WG;            // 0..127
        for (int idx = tid; idx < 12 * 1024; idx += 256) {
            int k = idx & 1023, row = idx >> 10;
            int jl = row / 3, g = row - 3 * jl;
            int jj = g * HH + jg * 4 + jl;
            lds[k * 16 + jl * 4 + g] = (k < HH) ? wih1[(size_t)jj * HH + k]
                                                : whh1[(size_t)jj * HH + (k - HH)];
        }
        const int j = jg * 4 + w;
        const float br  = bih1[j] + bhh1[j];
        const float bz  = bih1[HH + j] + bhh1[HH + j];
        const float bnx = bih1[2 * HH + j], bnh = bhh1[2 * HH + j];
        __syncthreads();

        for (int t = 0; t <= TT; ++t) {
            if (t >= 1) {
                const float* y0  = hT0 + (size_t)((t + 1) & 1) * HH * BB;  // h0 state t-1
                const float* h1i = hT1 + (size_t)(t & 1) * HH * BB;        // h1 state t-2
                float*       h1o = hT1 + (size_t)((t + 1) & 1) * HH * BB;
                const float hold = h1i[j * 64 + lane];
                float ar = 0.f, az = 0.f, anx = 0.f, anh = 0.f;
                #pragma unroll 8
                for (int k = 0; k < HH; ++k) {
                    const float hv = y0[k * 64 + lane];
                    const float4 wv = lds4[k * 4 + w];
                    ar += wv.x * hv; az += wv.y * hv; anx += wv.z * hv;
                }
                #pragma unroll 8
                for (int k = 0; k < HH; ++k) {
                    const float hv = h1i[k * 64 + lane];
                    const float4 wv = lds4[(HH + k) * 4 + w];
                    ar += wv.x * hv; az += wv.y * hv; anh += wv.z * hv;
                }
                const float r = sigm(ar + br);
                const float z = sigm(az + bz);
                const float n = tanhf(anx + bnx + r * (anh + bnh));
                h1o[j * 64 + lane] = (1.0f - z) * n + z * hold;
            }
            grid_barrier(cnt, t, tid);
        }
    }
}

// out[l][b][j] = hTl[buf1][j][b]
__global__ __launch_bounds__(256) void copy_out_k(const float* __restrict__ ws,
                                                  float* __restrict__ out) {
    int i = blockIdx.x * 256 + threadIdx.x;   // grid covers exactly 2*BB*HH
    int l = i >> 15;
    int r = i & 32767;
    int b = r >> 9;
    int j = r & 511;
    out[i] = ws[(size_t)l * 2 * HH * BB + HH * BB + j * 64 + b];
}

extern "C" void kernel_launch(void* const* d_in, const int* in_sizes, int n_in,
                              void* d_out, int out_size, void* d_ws, size_t ws_size,
                              hipStream_t stream)
{
    const float* x    = (const float*)d_in[0];
    const float* wih0 = (const float*)d_in[1];
    const float* whh0 = (const float*)d_in[2];
    const float* bih0 = (const float*)d_in[3];
    const float* bhh0 = (const float*)d_in[4];
    const float* wih1 = (const float*)d_in[5];
    const float* whh1 = (const float*)d_in[6];
    const float* bih1 = (const float*)d_in[7];
    const float* bhh1 = (const float*)d_in[8];
    float* out = (float*)d_out;
    float* ws  = (float*)d_ws;

    // zero h rings + cnt (131073 floats, rounded up)
    zero_k<<<(131328) / 256, 256, 0, stream>>>(ws, 131073);
    gru_persist<<<NWG, 256, 0, stream>>>(x, wih0, whh0, bih0, bhh0,
                                         wih1, whh1, bih1, bhh1, ws);
    copy_out_k<<<(2 * BB * HH) / 256, 256, 0, stream>>>(ws, out);
}

// Round 5
// 176518.982 us; speedup vs baseline: 1.3276x; 1.3276x over previous
//
#include <hip/hip_runtime.h>
#include <math.h>

// 2-layer GRU, T=4096, B=64, H=512, input=1. Output = final hidden (2,64,512) f32.
//
// R5 (= R4 with fence builtin fixed): persistent kernel, contention-free grid
// barrier: per-WG padded arrive flags (release store, own cacheline) ->
// master WG gathers 192 flags in parallel (relaxed loads + acquire fence) ->
// single epoch word release-broadcast; workers poll epoch relaxed + acquire
// fence. Replaces R3's single-cacheline fetch_add (192 serialized cross-XCD
// RMWs ~= 50 us/step, measured: VALUBusy 6.2%).
//   L0: WGs [0,64):  8 j per WG (wave w owns j0=jg*8+2w, j1=j0+1), K=512
//   L1: WGs [64,192): 4 j per WG (wave w owns j=jg*4+w), K=1024 (y0 | h1)
// Software skew: iter t computes L0 state t and L1 state t-1.
// ws: hT0[2][512][64] | hT1[2][512][64] | flags[192*32 u32] | epoch (u32)

#define TT 4096
#define BB 64
#define HH 512
#define NWG 192
#define L0WG 64
#define PADU 32   // u32 stride between arrive flags (128 B)

__device__ __forceinline__ float sigm(float v) { return 1.0f / (1.0f + expf(-v)); }

__device__ __forceinline__ void fence_acq_agent() {
    __builtin_amdgcn_fence(__ATOMIC_ACQUIRE, "agent");
}

__global__ __launch_bounds__(256) void zero_k(float* p, int n) {
    int i = blockIdx.x * 256 + threadIdx.x;
    if (i < n) p[i] = 0.0f;
}

__device__ __forceinline__ void grid_barrier2(unsigned* flags, unsigned* epoch,
                                              int wg, int tid, unsigned tgt,
                                              bool master) {
    __syncthreads();  // all waves' stores issued before arrive
    if (tid == 0)
        __hip_atomic_store(&flags[wg * PADU], tgt, __ATOMIC_RELEASE,
                           __HIP_MEMORY_SCOPE_AGENT);
    if (master && tid < 64) {
        for (;;) {
            unsigned a = __hip_atomic_load(&flags[tid * PADU], __ATOMIC_RELAXED,
                                           __HIP_MEMORY_SCOPE_AGENT);
            unsigned b = __hip_atomic_load(&flags[(tid + 64) * PADU], __ATOMIC_RELAXED,
                                           __HIP_MEMORY_SCOPE_AGENT);
            unsigned c = __hip_atomic_load(&flags[(tid + 128) * PADU], __ATOMIC_RELAXED,
                                           __HIP_MEMORY_SCOPE_AGENT);
            if (__all(a >= tgt && b >= tgt && c >= tgt)) break;
            __builtin_amdgcn_s_sleep(1);
        }
        if (tid == 0) {
            fence_acq_agent();
            __hip_atomic_store(epoch, tgt, __ATOMIC_RELEASE,
                               __HIP_MEMORY_SCOPE_AGENT);
        }
    }
    if (tid == 0) {
        while (__hip_atomic_load(epoch, __ATOMIC_RELAXED,
                                 __HIP_MEMORY_SCOPE_AGENT) < tgt)
            __builtin_amdgcn_s_sleep(2);
        fence_acq_agent();
    }
    __syncthreads();
}

__global__ __launch_bounds__(256) void gru_persist(
    const float* __restrict__ x,
    const float* __restrict__ wih0, const float* __restrict__ whh0,
    const float* __restrict__ bih0, const float* __restrict__ bhh0,
    const float* __restrict__ wih1, const float* __restrict__ whh1,
    const float* __restrict__ bih1, const float* __restrict__ bhh1,
    float* __restrict__ ws)
{
    __shared__ float4 lds4[4096];          // 64 KB
    float* lds = (float*)lds4;
    float* hT0 = ws;                        // [2][512][64]
    float* hT1 = ws + 2 * HH * BB;          // [2][512][64]
    unsigned* flags = (unsigned*)(ws + 4 * HH * BB);
    unsigned* epoch = flags + NWG * PADU;

    const int tid  = threadIdx.x;
    const int lane = tid & 63;              // batch index
    const int w    = tid >> 6;              // wave 0..3
    const int id   = blockIdx.x;
    const bool master = (id == NWG - 1);    // an L1 WG (late finisher)

    if (id < L0WG) {
        // ================= Layer 0 =================
        const int jg = id;
        for (int idx = tid; idx < 24 * 512; idx += 256) {
            int k = idx & 511, row = idx >> 9;
            int jl = row / 3, g = row - 3 * jl;
            lds[k * 32 + jl * 4 + g] = whh0[(size_t)(g * HH + jg * 8 + jl) * HH + k];
        }
        const int j0 = jg * 8 + w * 2, j1 = j0 + 1;
        const float wir0 = wih0[j0], wiz0 = wih0[HH + j0], win0 = wih0[2 * HH + j0];
        const float wir1 = wih0[j1], wiz1 = wih0[HH + j1], win1 = wih0[2 * HH + j1];
        const float br0  = bih0[j0] + bhh0[j0];
        const float bz0  = bih0[HH + j0] + bhh0[HH + j0];
        const float bnx0 = bih0[2 * HH + j0], bnh0 = bhh0[2 * HH + j0];
        const float br1  = bih0[j1] + bhh0[j1];
        const float bz1  = bih0[HH + j1] + bhh0[HH + j1];
        const float bnx1 = bih0[2 * HH + j1], bnh1 = bhh0[2 * HH + j1];
        __syncthreads();

        for (int t = 0; t <= TT; ++t) {
            if (t < TT) {
                const float* hin  = hT0 + (size_t)((t + 1) & 1) * HH * BB;
                float*       hout = hT0 + (size_t)(t & 1) * HH * BB;
                const float xv    = x[(size_t)t * BB + lane];
                const float hold0 = hin[j0 * 64 + lane];
                const float hold1 = hin[j1 * 64 + lane];
                float a0r = 0.f, a0z = 0.f, a0n = 0.f;
                float a1r = 0.f, a1z = 0.f, a1n = 0.f;
                #pragma unroll 8
                for (int k = 0; k < HH; ++k) {
                    const float hv = hin[k * 64 + lane];
                    const float4 wA = lds4[k * 8 + w * 2];
                    const float4 wB = lds4[k * 8 + w * 2 + 1];
                    a0r += wA.x * hv; a0z += wA.y * hv; a0n += wA.z * hv;
                    a1r += wB.x * hv; a1z += wB.y * hv; a1n += wB.z * hv;
                }
                {
                    const float r = sigm(xv * wir0 + br0 + a0r);
                    const float z = sigm(xv * wiz0 + bz0 + a0z);
                    const float n = tanhf(xv * win0 + bnx0 + r * (a0n + bnh0));
                    hout[j0 * 64 + lane] = (1.0f - z) * n + z * hold0;
                }
                {
                    const float r = sigm(xv * wir1 + br1 + a1r);
                    const float z = sigm(xv * wiz1 + bz1 + a1z);
                    const float n = tanhf(xv * win1 + bnx1 + r * (a1n + bnh1));
                    hout[j1 * 64 + lane] = (1.0f - z) * n + z * hold1;
                }
            }
            if (t < TT) grid_barrier2(flags, epoch, id, tid, (unsigned)(t + 1), master);
        }
    } else {
        // ================= Layer 1 =================
        const int jg = id - L0WG;            // 0..127
        for (int idx = tid; idx < 12 * 1024; idx += 256) {
            int k = idx & 1023, row = idx >> 10;
            int jl = row / 3, g = row - 3 * jl;
            int jj = g * HH + jg * 4 + jl;
            lds[k * 16 + jl * 4 + g] = (k < HH) ? wih1[(size_t)jj * HH + k]
                                                : whh1[(size_t)jj * HH + (k - HH)];
        }
        const int j = jg * 4 + w;
        const float br  = bih1[j] + bhh1[j];
        const float bz  = bih1[HH + j] + bhh1[HH + j];
        const float bnx = bih1[2 * HH + j], bnh = bhh1[2 * HH + j];
        __syncthreads();

        for (int t = 0; t <= TT; ++t) {
            if (t >= 1) {
                const float* y0  = hT0 + (size_t)((t + 1) & 1) * HH * BB;  // h0 state t-1
                const float* h1i = hT1 + (size_t)(t & 1) * HH * BB;        // h1 state t-2
                float*       h1o = hT1 + (size_t)((t + 1) & 1) * HH * BB;
                const float hold = h1i[j * 64 + lane];
                float ar = 0.f, az = 0.f, anx = 0.f, anh = 0.f;
                #pragma unroll 8
                for (int k = 0; k < HH; ++k) {
                    const float hv = y0[k * 64 + lane];
                    const float4 wv = lds4[k * 4 + w];
                    ar += wv.x * hv; az += wv.y * hv; anx += wv.z * hv;
                }
                #pragma unroll 8
                for (int k = 0; k < HH; ++k) {
                    const float hv = h1i[k * 64 + lane];
                    const float4 wv = lds4[(HH + k) * 4 + w];
                    ar += wv.x * hv; az += wv.y * hv; anh += wv.z * hv;
                }
                const float r = sigm(ar + br);
                const float z = sigm(az + bz);
                const float n = tanhf(anx + bnx + r * (anh + bnh));
                h1o[j * 64 + lane] = (1.0f - z) * n + z * hold;
            }
            if (t < TT) grid_barrier2(flags, epoch, id, tid, (unsigned)(t + 1), master);
        }
    }
}

// out[l][b][j] = hTl[buf1][j][b]
__global__ __launch_bounds__(256) void copy_out_k(const float* __restrict__ ws,
                                                  float* __restrict__ out) {
    int i = blockIdx.x * 256 + threadIdx.x;   // grid covers exactly 2*BB*HH
    int l = i >> 15;
    int r = i & 32767;
    int b = r >> 9;
    int j = r & 511;
    out[i] = ws[(size_t)l * 2 * HH * BB + HH * BB + j * 64 + b];
}

extern "C" void kernel_launch(void* const* d_in, const int* in_sizes, int n_in,
                              void* d_out, int out_size, void* d_ws, size_t ws_size,
                              hipStream_t stream)
{
    const float* x    = (const float*)d_in[0];
    const float* wih0 = (const float*)d_in[1];
    const float* whh0 = (const float*)d_in[2];
    const float* bih0 = (const float*)d_in[3];
    const float* bhh0 = (const float*)d_in[4];
    const float* wih1 = (const float*)d_in[5];
    const float* whh1 = (const float*)d_in[6];
    const float* bih1 = (const float*)d_in[7];
    const float* bhh1 = (const float*)d_in[8];
    float* out = (float*)d_out;
    float* ws  = (float*)d_ws;

    // zero h rings + flags + epoch
    const int nzero = 4 * HH * BB + NWG * PADU + 1;   // 137217 words
    zero_k<<<(nzero + 255) / 256, 256, 0, stream>>>(ws, nzero);
    gru_persist<<<NWG, 256, 0, stream>>>(x, wih0, whh0, bih0, bhh0,
                                         wih1, whh1, bih1, bhh1, ws);
    copy_out_k<<<(2 * BB * HH) / 256, 256, 0, stream>>>(ws, out);
}

// Round 6
// 84565.002 us; speedup vs baseline: 2.7712x; 2.0874x over previous
//
#include <hip/hip_runtime.h>
#include <math.h>

// 2-layer GRU, T=4096, B=64, H=512, input=1. Output = final hidden (2,64,512) f32.
//
// R6: persistent kernel, FENCE-FREE cross-WG coherence. All shared state
// (h rings, flags, epoch) uses relaxed agent-scope atomics (sc1: bypass
// L1/L2, served by LLC = coherence point). No release/acquire fences ->
// no buffer_wbl2/buffer_inv per step (R3/R5's ~40us/step cost).
// Ordering: __syncthreads drains vmcnt per wave; flag stored after; readers
// gated by poll control-dependency. Single LLC serialization point.
//
// k-loop split across the 4 waves (no L1-cache reuse exists with sc1 loads):
//   L0 WG (id<64):  8 j, wave w sums k in [w*128,(w+1)*128); LDS-reduce x2 rounds
//   L1 WG (id>=64): 4 j, wave w sums k in [w*256,(w+1)*256) of K=1024 (y0|h1);
//                   waves 0,1 read y0, waves 2,3 read h1; LDS-reduce x1 round
// Software skew: iter t computes L0 state t and L1 state t-1.
// ws: hT0[2][512][64] | hT1[2][512][64] | flags[192*32 u32] | epoch

#define TT 4096
#define BB 64
#define HH 512
#define HB (HH * BB)
#define NWG 192
#define L0WG 64
#define PADU 32

__device__ __forceinline__ float sigm(float v) { return 1.0f / (1.0f + expf(-v)); }

__device__ __forceinline__ float aldf(const float* p) {
    return __hip_atomic_load((float*)p, __ATOMIC_RELAXED, __HIP_MEMORY_SCOPE_AGENT);
}
__device__ __forceinline__ void astf(float* p, float v) {
    __hip_atomic_store(p, v, __ATOMIC_RELAXED, __HIP_MEMORY_SCOPE_AGENT);
}
__device__ __forceinline__ unsigned aldu(const unsigned* p) {
    return __hip_atomic_load((unsigned*)p, __ATOMIC_RELAXED, __HIP_MEMORY_SCOPE_AGENT);
}
__device__ __forceinline__ void astu(unsigned* p, unsigned v) {
    __hip_atomic_store(p, v, __ATOMIC_RELAXED, __HIP_MEMORY_SCOPE_AGENT);
}

__global__ __launch_bounds__(256) void zero_k(float* p, int n) {
    int i = blockIdx.x * 256 + threadIdx.x;
    if (i < n) p[i] = 0.0f;
}

__device__ __forceinline__ void gbar(unsigned* flags, unsigned* epoch,
                                     int wg, int tid, unsigned tgt, bool master) {
    __syncthreads();   // all waves reached; per-wave vmcnt drained (stores acked at LLC)
    if (tid == 0) {
        asm volatile("s_waitcnt vmcnt(0)" ::: "memory");
        astu(&flags[wg * PADU], tgt);
    }
    if (master && tid < 64) {
        for (;;) {
            unsigned a = aldu(&flags[tid * PADU]);
            unsigned b = aldu(&flags[(tid + 64) * PADU]);
            unsigned c = aldu(&flags[(tid + 128) * PADU]);
            if (__all(a >= tgt && b >= tgt && c >= tgt)) break;
            __builtin_amdgcn_s_sleep(1);
        }
        if (tid == 0) astu(epoch, tgt);
    }
    if (tid == 0) {
        while (aldu(epoch) < tgt) __builtin_amdgcn_s_sleep(2);
    }
    __syncthreads();
}

__global__ __launch_bounds__(256) void gru_persist(
    const float* __restrict__ x,
    const float* __restrict__ wih0, const float* __restrict__ whh0,
    const float* __restrict__ bih0, const float* __restrict__ bhh0,
    const float* __restrict__ wih1, const float* __restrict__ whh1,
    const float* __restrict__ bih1, const float* __restrict__ bhh1,
    float* __restrict__ ws)
{
    __shared__ float wlds[12288];   // 48 KB weights
    __shared__ float red[3072];     // 12 KB cross-wave reduction

    float* hT0 = ws;
    float* hT1 = ws + 2 * HB;
    unsigned* flags = (unsigned*)(ws + 4 * HB);
    unsigned* epoch = flags + NWG * PADU;

    const int tid  = threadIdx.x;
    const int lane = tid & 63;              // batch index b
    const int w    = tid >> 6;              // wave 0..3
    const int id   = blockIdx.x;
    const bool master = (id == NWG - 1);

    if (id < L0WG) {
        // ===================== Layer 0 =====================
        const int jg = id;
        // stage whh0 -> wlds[k*24 + e], e = jl*3+g (jl 0..7), coalesced over k
        for (int idx = tid; idx < 24 * 512; idx += 256) {
            int e = idx >> 9, k = idx & 511;
            int jl = e / 3, g = e - 3 * jl;
            wlds[k * 24 + e] = whh0[(size_t)(g * HH + jg * 8 + jl) * HH + k];
        }
        // wave w's epilogue columns: jl = 2w, 2w+1
        const int ja = jg * 8 + 2 * w, jb = ja + 1;
        const float wirA = wih0[ja], wizA = wih0[HH + ja], winA = wih0[2 * HH + ja];
        const float wirB = wih0[jb], wizB = wih0[HH + jb], winB = wih0[2 * HH + jb];
        const float brA = bih0[ja] + bhh0[ja];
        const float bzA = bih0[HH + ja] + bhh0[HH + ja];
        const float bnxA = bih0[2 * HH + ja], bnhA = bhh0[2 * HH + ja];
        const float brB = bih0[jb] + bhh0[jb];
        const float bzB = bih0[HH + jb] + bhh0[HH + jb];
        const float bnxB = bih0[2 * HH + jb], bnhB = bhh0[2 * HH + jb];
        __syncthreads();

        for (int t = 0; t <= TT; ++t) {
            if (t < TT) {
                const float* hin  = hT0 + ((t + 1) & 1) * HB;
                float*       hout = hT0 + (t & 1) * HB;
                const float* hbase = hin + lane;
                float acc[24];
                #pragma unroll
                for (int e = 0; e < 24; ++e) acc[e] = 0.0f;
                const int kb = w * 128;
                for (int c = 0; c < 4; ++c) {
                    const int k0 = kb + c * 32;
                    #pragma unroll
                    for (int i = 0; i < 32; ++i) {
                        const int k = k0 + i;
                        const float hv = aldf(hbase + k * 64);
                        const float4* wp = (const float4*)&wlds[k * 24];
                        const float4 q0 = wp[0], q1 = wp[1], q2 = wp[2];
                        const float4 q3 = wp[3], q4 = wp[4], q5 = wp[5];
                        acc[0] += q0.x * hv; acc[1] += q0.y * hv; acc[2] += q0.z * hv; acc[3] += q0.w * hv;
                        acc[4] += q1.x * hv; acc[5] += q1.y * hv; acc[6] += q1.z * hv; acc[7] += q1.w * hv;
                        acc[8] += q2.x * hv; acc[9] += q2.y * hv; acc[10] += q2.z * hv; acc[11] += q2.w * hv;
                        acc[12] += q3.x * hv; acc[13] += q3.y * hv; acc[14] += q3.z * hv; acc[15] += q3.w * hv;
                        acc[16] += q4.x * hv; acc[17] += q4.y * hv; acc[18] += q4.z * hv; acc[19] += q4.w * hv;
                        acc[20] += q5.x * hv; acc[21] += q5.y * hv; acc[22] += q5.z * hv; acc[23] += q5.w * hv;
                    }
                }
                // cross-wave reduction, round 1: e 0..11 (jl 0..3)
                float4* r4 = (float4*)red;
                const int rb4 = (w * 64 + lane) * 3;
                r4[rb4 + 0] = make_float4(acc[0], acc[1], acc[2], acc[3]);
                r4[rb4 + 1] = make_float4(acc[4], acc[5], acc[6], acc[7]);
                r4[rb4 + 2] = make_float4(acc[8], acc[9], acc[10], acc[11]);
                __syncthreads();
                float sA0 = 0.f, sA1 = 0.f, sA2 = 0.f, sB0 = 0.f, sB1 = 0.f, sB2 = 0.f;
                if (w < 2) {
                    #pragma unroll
                    for (int wp_ = 0; wp_ < 4; ++wp_) {
                        const float* rb = &red[(wp_ * 64 + lane) * 12 + 6 * w];
                        sA0 += rb[0]; sA1 += rb[1]; sA2 += rb[2];
                        sB0 += rb[3]; sB1 += rb[4]; sB2 += rb[5];
                    }
                }
                __syncthreads();
                // round 2: e 12..23 (jl 4..7)
                r4[rb4 + 0] = make_float4(acc[12], acc[13], acc[14], acc[15]);
                r4[rb4 + 1] = make_float4(acc[16], acc[17], acc[18], acc[19]);
                r4[rb4 + 2] = make_float4(acc[20], acc[21], acc[22], acc[23]);
                __syncthreads();
                if (w >= 2) {
                    #pragma unroll
                    for (int wp_ = 0; wp_ < 4; ++wp_) {
                        const float* rb = &red[(wp_ * 64 + lane) * 12 + 6 * (w - 2)];
                        sA0 += rb[0]; sA1 += rb[1]; sA2 += rb[2];
                        sB0 += rb[3]; sB1 += rb[4]; sB2 += rb[5];
                    }
                }
                // epilogue: 2 outputs per thread
                const float xv = x[(size_t)t * BB + lane];
                const float holdA = aldf(&hin[ja * 64 + lane]);
                const float holdB = aldf(&hin[jb * 64 + lane]);
                {
                    const float r = sigm(xv * wirA + brA + sA0);
                    const float z = sigm(xv * wizA + bzA + sA1);
                    const float n = tanhf(xv * winA + bnxA + r * (sA2 + bnhA));
                    astf(&hout[ja * 64 + lane], (1.0f - z) * n + z * holdA);
                }
                {
                    const float r = sigm(xv * wirB + brB + sB0);
                    const float z = sigm(xv * wizB + bzB + sB1);
                    const float n = tanhf(xv * winB + bnxB + r * (sB2 + bnhB));
                    astf(&hout[jb * 64 + lane], (1.0f - z) * n + z * holdB);
                }
            }
            if (t < TT) gbar(flags, epoch, id, tid, (unsigned)(t + 1), master);
        }
    } else {
        // ===================== Layer 1 =====================
        const int jg = id - L0WG;            // 0..127
        // stage [wih1; whh1] -> wlds[k*12 + e], e = jl*3+g (jl 0..3), K=1024
        for (int idx = tid; idx < 12 * 1024; idx += 256) {
            int e = idx >> 10, k = idx & 1023;
            int jl = e / 3, g = e - 3 * jl;
            int row = g * HH + jg * 4 + jl;
            wlds[k * 12 + e] = (k < HH) ? wih1[(size_t)row * HH + k]
                                        : whh1[(size_t)row * HH + (k - HH)];
        }
        const int j = jg * 4 + w;
        const float br  = bih1[j] + bhh1[j];
        const float bz  = bih1[HH + j] + bhh1[HH + j];
        const float bnx = bih1[2 * HH + j], bnh = bhh1[2 * HH + j];
        __syncthreads();

        for (int t = 0; t <= TT; ++t) {
            if (t >= 1) {
                const float* y0  = hT0 + ((t + 1) & 1) * HB;  // h0 state t-1
                const float* h1i = hT1 + (t & 1) * HB;        // h1 state t-2
                float*       h1o = hT1 + ((t + 1) & 1) * HB;
                float acc[12];
                #pragma unroll
                for (int e = 0; e < 12; ++e) acc[e] = 0.0f;
                const int kb = w * 256;                       // 0,256,512,768
                const float* src = (w < 2) ? (y0 + lane) : (h1i + lane);
                const int koff = (w < 2) ? kb : (kb - 512);   // index within src ring
                for (int c = 0; c < 8; ++c) {
                    const int ks = koff + c * 32;
                    const int kw = kb + c * 32;
                    #pragma unroll
                    for (int i = 0; i < 32; ++i) {
                        const float hv = aldf(src + (ks + i) * 64);
                        const float4* wp = (const float4*)&wlds[(kw + i) * 12];
                        const float4 q0 = wp[0], q1 = wp[1], q2 = wp[2];
                        acc[0] += q0.x * hv; acc[1] += q0.y * hv; acc[2] += q0.z * hv; acc[3] += q0.w * hv;
                        acc[4] += q1.x * hv; acc[5] += q1.y * hv; acc[6] += q1.z * hv; acc[7] += q1.w * hv;
                        acc[8] += q2.x * hv; acc[9] += q2.y * hv; acc[10] += q2.z * hv; acc[11] += q2.w * hv;
                    }
                }
                // single-round cross-wave reduction
                float4* r4 = (float4*)red;
                const int rb4 = (w * 64 + lane) * 3;
                r4[rb4 + 0] = make_float4(acc[0], acc[1], acc[2], acc[3]);
                r4[rb4 + 1] = make_float4(acc[4], acc[5], acc[6], acc[7]);
                r4[rb4 + 2] = make_float4(acc[8], acc[9], acc[10], acc[11]);
                __syncthreads();
                float sr = 0.f, sz = 0.f, snx = 0.f, snh = 0.f;
                #pragma unroll
                for (int wp_ = 0; wp_ < 4; ++wp_) {
                    const float* rb = &red[(wp_ * 64 + lane) * 12 + 3 * w];
                    sr += rb[0]; sz += rb[1];
                    if (wp_ < 2) snx += rb[2]; else snh += rb[2];
                }
                const float hold = aldf(&h1i[j * 64 + lane]);
                const float r = sigm(sr + br);
                const float z = sigm(sz + bz);
                const float n = tanhf(snx + bnx + r * (snh + bnh));
                astf(&h1o[j * 64 + lane], (1.0f - z) * n + z * hold);
                __syncthreads();   // red reuse guard before next step's stores
            }
            if (t < TT) gbar(flags, epoch, id, tid, (unsigned)(t + 1), master);
        }
    }
}

// out[l][b][j] = hTl[buf1][j][b]
__global__ __launch_bounds__(256) void copy_out_k(const float* __restrict__ ws,
                                                  float* __restrict__ out) {
    int i = blockIdx.x * 256 + threadIdx.x;
    int l = i >> 15;
    int r = i & 32767;
    int b = r >> 9;
    int j = r & 511;
    out[i] = ws[(size_t)l * 2 * HB + HB + j * 64 + b];
}

extern "C" void kernel_launch(void* const* d_in, const int* in_sizes, int n_in,
                              void* d_out, int out_size, void* d_ws, size_t ws_size,
                              hipStream_t stream)
{
    const float* x    = (const float*)d_in[0];
    const float* wih0 = (const float*)d_in[1];
    const float* whh0 = (const float*)d_in[2];
    const float* bih0 = (const float*)d_in[3];
    const float* bhh0 = (const float*)d_in[4];
    const float* wih1 = (const float*)d_in[5];
    const float* whh1 = (const float*)d_in[6];
    const float* bih1 = (const float*)d_in[7];
    const float* bhh1 = (const float*)d_in[8];
    float* out = (float*)d_out;
    float* ws  = (float*)d_ws;

    const int nzero = 4 * HB + NWG * PADU + 1;   // rings + flags + epoch
    zero_k<<<(nzero + 255) / 256, 256, 0, stream>>>(ws, nzero);
    gru_persist<<<NWG, 256, 0, stream>>>(x, wih0, whh0, bih0, bhh0,
                                         wih1, whh1, bih1, bhh1, ws);
    copy_out_k<<<(2 * BB * HH) / 256, 256, 0, stream>>>(ws, out);
}